// Round 4
// baseline (705.181 us; speedup 1.0000x reference)
//
#include <hip/hip_runtime.h>
#include <hip/hip_bf16.h>

#define TLEN 4096
#define EDIM 2048
#define DDIM 128
#define BSZ  8
#define NT   32            // TLEN/128
#define MROWS (BSZ*TLEN)   // 32768
#define NSLOT 528          // NT*(NT+1)/2 lower-tri tiles per batch

typedef unsigned short u16;
typedef __attribute__((ext_vector_type(8))) short bf16x8;  // 8 bf16 in 4 VGPRs
typedef __attribute__((ext_vector_type(4))) float f32x4;

// exp(scale * s) = exp2(C1 * s), scale = 1/sqrt(128)
#define C1F (0.08838834764831845f * 1.4426950408889634f)

__device__ __forceinline__ u16 f2bf(float f) {
  unsigned u = __builtin_bit_cast(unsigned, f);
  u += 0x7FFFu + ((u >> 16) & 1u);   // RNE
  return (u16)(u >> 16);
}
__device__ __forceinline__ float bf2f(u16 h) {
  unsigned u = ((unsigned)h) << 16;
  return __builtin_bit_cast(float, u);
}

__device__ __forceinline__ void async_ld16(const void* g, void* lds) {
  __builtin_amdgcn_global_load_lds(
      (const __attribute__((address_space(1))) unsigned int*)(g),
      (__attribute__((address_space(3))) unsigned int*)(lds), 16, 0, 0);
}

// XOR-swizzled byte offsets (verified R2/R3: 0 bank conflicts)
__device__ __forceinline__ int swz16(int row, int chunk) {   // 256B rows
  return row * 256 + ((chunk ^ (row & 15)) << 4);
}
__device__ __forceinline__ int swz8(int row, int chunk) {    // 128B rows
  return row * 128 + ((chunk ^ (row & 7)) << 4);
}

// ---------------------------------------------------------------------------
__global__ __launch_bounds__(256) void zero_f32(float* __restrict__ out,
                                                float* __restrict__ denom) {
  size_t i = (size_t)blockIdx.x * 256 + threadIdx.x;
  float4 z = {0.f, 0.f, 0.f, 0.f};
  if (i < (size_t)MROWS * DDIM / 4) ((float4*)out)[i] = z;
  if (i < (size_t)BSZ * TLEN / 4) ((float4*)denom)[i] = z;
}

// ---------------------------------------------------------------------------
// Wt[w][n][k] = bf16(W_w[k][n])
__global__ __launch_bounds__(256) void prep_w(const float* __restrict__ Wq,
                                              const float* __restrict__ Wk,
                                              const float* __restrict__ Wv,
                                              u16* __restrict__ Wt) {
  int g = blockIdx.x * 256 + threadIdx.x;
  int w = g >> 15;
  int rem = g & 32767;
  int n = rem >> 8;
  int k0 = (rem & 255) * 8;
  const float* W = (w == 0) ? Wq : (w == 1) ? Wk : Wv;
  unsigned pk[4];
  for (int i = 0; i < 4; ++i) {
    u16 lo = f2bf(W[(size_t)(k0 + 2 * i) * DDIM + n]);
    u16 hi = f2bf(W[(size_t)(k0 + 2 * i + 1) * DDIM + n]);
    pk[i] = (unsigned)lo | ((unsigned)hi << 16);
  }
  uint4 v; v.x = pk[0]; v.y = pk[1]; v.z = pk[2]; v.w = pk[3];
  *(uint4*)(Wt + ((size_t)(w * DDIM + n) * EDIM + k0)) = v;
}

// ---------------------------------------------------------------------------
// Fused q,k,v GEMM. LB(512,1): (512,2) capped VGPR at 128 < 96 acc + frags.
__global__ __launch_bounds__(512, 1) void qkv_gemm(const float* __restrict__ x,
                                                   const u16* __restrict__ Wt,
                                                   u16* __restrict__ qkvb) {
  __shared__ u16 As[128 * 64];
  __shared__ u16 Bs[384 * 64];
  const int tid = threadIdx.x, lane = tid & 63, wave = tid >> 6;
  const int quad = lane >> 4, l15 = lane & 15;
  const int m0 = blockIdx.x * 128;
  const int wm = wave & 1, wn = wave >> 1;

  const f32x4 zero = {0.f, 0.f, 0.f, 0.f};
  f32x4 acc[4][6];
  for (int mi = 0; mi < 4; ++mi)
    for (int ni = 0; ni < 6; ++ni) acc[mi][ni] = zero;

  int arow[4], af4[4];
  for (int i = 0; i < 4; ++i) {
    int c = i * 512 + tid;
    arow[i] = c >> 4;
    af4[i] = c & 15;
  }
  float4 ap[4];
#define LOADA(KT)                                                            \
  for (int i = 0; i < 4; ++i)                                                \
    ap[i] = *(const float4*)(x + (size_t)(m0 + arow[i]) * EDIM + (KT)*64 +   \
                             af4[i] * 4);
  LOADA(0)

  for (int kt = 0; kt < EDIM / 64; ++kt) {
    __syncthreads();
    for (int i = 0; i < 4; ++i) {
      uint2 pk;
      pk.x = (unsigned)f2bf(ap[i].x) | ((unsigned)f2bf(ap[i].y) << 16);
      pk.y = (unsigned)f2bf(ap[i].z) | ((unsigned)f2bf(ap[i].w) << 16);
      *(uint2*)((char*)As + swz8(arow[i], af4[i] >> 1) + (af4[i] & 1) * 8) = pk;
    }
    {
      const int k0 = kt * 64;
      for (int e = 0; e < 6; ++e) {
        int rb = (wave * 6 + e) * 8;
        int r = rb + (lane >> 3);
        int c = (lane & 7) ^ (r & 7);
        async_ld16((const char*)(Wt + (size_t)r * EDIM + k0) + c * 16,
                   (char*)Bs + rb * 128);
      }
    }
    __builtin_amdgcn_s_waitcnt(0);
    __syncthreads();
    if (kt + 1 < EDIM / 64) { LOADA(kt + 1) }
    for (int ks = 0; ks < 2; ++ks) {
      const int ch = ks * 4 + quad;
      bf16x8 afr[4], bfr[6];
      for (int mi = 0; mi < 4; ++mi)
        afr[mi] = *(const bf16x8*)((char*)As + swz8(wm * 64 + mi * 16 + l15, ch));
      for (int ni = 0; ni < 6; ++ni)
        bfr[ni] = *(const bf16x8*)((char*)Bs + swz8(wn * 96 + ni * 16 + l15, ch));
      for (int mi = 0; mi < 4; ++mi)
        for (int ni = 0; ni < 6; ++ni)
          acc[mi][ni] = __builtin_amdgcn_mfma_f32_16x16x32_bf16(afr[mi], bfr[ni], acc[mi][ni], 0, 0, 0);
    }
  }
#undef LOADA
  for (int mi = 0; mi < 4; ++mi)
    for (int ni = 0; ni < 6; ++ni) {
      int n = wn * 96 + ni * 16 + l15;
      u16* ob = qkvb + (size_t)(n >> 7) * MROWS * DDIM;
      int nc = n & 127;
      for (int r = 0; r < 4; ++r) {
        int row = m0 + wm * 64 + mi * 16 + quad * 4 + r;
        ob[(size_t)row * DDIM + nc] = f2bf(acc[mi][ni][r]);
      }
    }
}

// ---------------------------------------------------------------------------
// score_k v2: computes S^T (A = K rows -> C rows = j, B = Q rows -> C cols = i).
// Wave w owns i-slice [w*32, w*32+32) and the FULL j range (acc[8][2]).
// C/D reg r runs along j (contiguous axis of row-major E) -> direct packed
// 8B register->global E stores. Q frags are direct global loads (no reuse).
// K (reused by all waves every ks) stays in LDS. K-loop: ZERO barriers,
// ZERO LDS round-trips, no vmcnt(0) drains -> compiler pipelines freely.
__global__ __launch_bounds__(256, 2) void score_k(const u16* __restrict__ qb,
                                                  const u16* __restrict__ kb,
                                                  char* __restrict__ Epack,
                                                  float* __restrict__ denom) {
  __shared__ u16 Kbuf[128 * 128];
  __shared__ float red[512];
  const int tid = threadIdx.x, lane = tid & 63, wave = tid >> 6;
  const int quad = lane >> 4, l15 = lane & 15;
  const int jt = blockIdx.x, ic = blockIdx.y, b = blockIdx.z;
  const int len = NT - jt;
  const int cl = (len + 3) >> 2;
  if (ic * cl >= len) return;
  const int beg = jt + ic * cl;
  const int end = (beg + cl < NT) ? beg + cl : NT;
  const int j0 = jt * 128;

  {  // stage K tile once (swizzled)
    const char* gk = (const char*)kb + ((size_t)b * TLEN + j0) * 256;
    for (int e = 0; e < 8; ++e) {
      int rb = (wave * 8 + e) * 4;
      int r = rb + (lane >> 4);
      int c = l15 ^ (r & 15);
      async_ld16(gk + r * 256 + c * 16, (char*)Kbuf + rb * 256);
    }
  }
  __builtin_amdgcn_s_waitcnt(0);
  __syncthreads();

  float csum[8][4];
  for (int mi = 0; mi < 8; ++mi)
    for (int r = 0; r < 4; ++r) csum[mi][r] = 0.f;
  const f32x4 zero = {0.f, 0.f, 0.f, 0.f};
  const char* qtile0 = (const char*)qb + (size_t)b * TLEN * 256;

  for (int it = beg; it < end; ++it) {
    const int i0 = it * 128;
    const char* gq = qtile0 + (size_t)i0 * 256;
    f32x4 acc[8][2];
    for (int mi = 0; mi < 8; ++mi)
      for (int ni = 0; ni < 2; ++ni) acc[mi][ni] = zero;
    for (int ks = 0; ks < 4; ++ks) {
      const int ch = ks * 4 + quad;
      bf16x8 kfr[8], qfr[2];
      for (int ni = 0; ni < 2; ++ni)
        qfr[ni] = *(const bf16x8*)(gq + (size_t)(wave * 32 + ni * 16 + l15) * 256 + ch * 16);
      for (int mi = 0; mi < 8; ++mi)
        kfr[mi] = *(const bf16x8*)((char*)Kbuf + swz16(mi * 16 + l15, ch));
      for (int mi = 0; mi < 8; ++mi)
        for (int ni = 0; ni < 2; ++ni)
          acc[mi][ni] = __builtin_amdgcn_mfma_f32_16x16x32_bf16(kfr[mi], qfr[ni], acc[mi][ni], 0, 0, 0);
    }
    const bool diag = (it == jt);
    char* eslot = Epack + (((size_t)b * NSLOT + (size_t)it * (it + 1) / 2 + jt) << 15);
    for (int mi = 0; mi < 8; ++mi) {
      const int jbase = mi * 16 + quad * 4;          // local j of r=0
      for (int ni = 0; ni < 2; ++ni) {
        const int il = wave * 32 + ni * 16 + l15;    // local i
        float ev[4];
        for (int r = 0; r < 4; ++r) {
          float e = __builtin_amdgcn_exp2f(C1F * acc[mi][ni][r]);
          if (diag && (i0 + il) < (j0 + jbase + r)) e = 0.f;
          csum[mi][r] += e;
          ev[r] = e;
        }
        uint2 pk;
        pk.x = (unsigned)f2bf(ev[0]) | ((unsigned)f2bf(ev[1]) << 16);
        pk.y = (unsigned)f2bf(ev[2]) | ((unsigned)f2bf(ev[3]) << 16);
        *(uint2*)(eslot + (size_t)il * 256 + jbase * 2) = pk;
      }
    }
  }
  // reduce csum over the 16 lanes of each quad (i-direction)
  for (int mi = 0; mi < 8; ++mi)
    for (int r = 0; r < 4; ++r) {
      float v = csum[mi][r];
      v += __shfl_xor(v, 1, 64);
      v += __shfl_xor(v, 2, 64);
      v += __shfl_xor(v, 4, 64);
      v += __shfl_xor(v, 8, 64);
      csum[mi][r] = v;
    }
  if (l15 == 0)
    for (int mi = 0; mi < 8; ++mi)
      for (int r = 0; r < 4; ++r)
        red[wave * 128 + mi * 16 + quad * 4 + r] = csum[mi][r];
  __syncthreads();
  if (tid < 128)
    atomicAdd(&denom[(size_t)b * TLEN + j0 + tid],
              red[tid] + red[128 + tid] + red[256 + tid] + red[384 + tid]);
}

// ---------------------------------------------------------------------------
// vbT[b][d][t] = vb[b][t][d] / denom[b][t]
__global__ __launch_bounds__(256) void vscale_t(const u16* __restrict__ vb,
                                                const float* __restrict__ denom,
                                                u16* __restrict__ vbT) {
  __shared__ u16 tile[128 * 136];
  const int tid = threadIdx.x;
  const int t0 = blockIdx.x * 128, b = blockIdx.y;
  for (int i = 0; i < 8; ++i) {
    int c = tid + i * 256;
    int tl = c >> 4, ch = c & 15;
    float rd = 1.0f / denom[(size_t)b * TLEN + t0 + tl];
    uint4 v = *(const uint4*)(vb + ((size_t)(b * TLEN + t0 + tl) * DDIM + ch * 8));
    unsigned w[4] = {v.x, v.y, v.z, v.w};
    unsigned o[4];
    for (int j = 0; j < 4; ++j) {
      float lo = bf2f((u16)w[j]) * rd;
      float hi = bf2f((u16)(w[j] >> 16)) * rd;
      o[j] = (unsigned)f2bf(lo) | ((unsigned)f2bf(hi) << 16);
    }
    uint4 ov; ov.x = o[0]; ov.y = o[1]; ov.z = o[2]; ov.w = o[3];
    *(uint4*)(tile + tl * 136 + ch * 8) = ov;
  }
  __syncthreads();
  for (int i = 0; i < 8; ++i) {
    int c = tid + i * 256;
    int d = c >> 4, ch = c & 15;
    unsigned pk[4];
    for (int j = 0; j < 4; ++j) {
      u16 lo = tile[(ch * 8 + 2 * j) * 136 + d];
      u16 hi = tile[(ch * 8 + 2 * j + 1) * 136 + d];
      pk[j] = (unsigned)lo | ((unsigned)hi << 16);
    }
    uint4 v; v.x = pk[0]; v.y = pk[1]; v.z = pk[2]; v.w = pk[3];
    *(uint4*)(vbT + ((size_t)(b * DDIM + d) * TLEN + t0 + ch * 8)) = v;
  }
}

// ---------------------------------------------------------------------------
// pv_k v2: out[b,i,:] (+)= E[i,:] @ V'^T. BARRIER-FREE, ZERO LDS: every
// E/V' 16B chunk feeds exactly one wave's fragment, so LDS staging buys
// nothing — direct global 16B fragment loads. K-step = 128 (one jt tile).
// Heavy blocks (it=31) dispatch first.
__global__ __launch_bounds__(256, 3) void pv_k(const char* __restrict__ Epack,
                                               const u16* __restrict__ vbT,
                                               float* __restrict__ out) {
  const int tid = threadIdx.x, lane = tid & 63, wave = tid >> 6;
  const int quad = lane >> 4, l15 = lane & 15;
  const int it = NT - 1 - blockIdx.x, jc = blockIdx.y, b = blockIdx.z;
  const int jtBeg = jc * 16;
  if (jtBeg > it) return;
  const int jtEnd = (jtBeg + 16 < it + 1) ? jtBeg + 16 : it + 1;
  const int i0 = it * 128;
  const int wm = wave & 1, wn = wave >> 1;

  const f32x4 zero = {0.f, 0.f, 0.f, 0.f};
  f32x4 accO[4][4];
  for (int mi = 0; mi < 4; ++mi)
    for (int ni = 0; ni < 4; ++ni) accO[mi][ni] = zero;

  const char* triBase = Epack + (((size_t)b * NSLOT + (size_t)it * (it + 1) / 2) << 15);
  const char* vbase = (const char*)vbT + (size_t)b * DDIM * TLEN * 2;

  for (int jt = jtBeg; jt < jtEnd; ++jt) {
    const char* eb = triBase + ((size_t)jt << 15);
    const char* vb2 = vbase + jt * 256;
    for (int ks = 0; ks < 4; ++ks) {
      const int choff = (ks * 4 + quad) * 16;
      bf16x8 afr[4], bfr[4];
      for (int mi = 0; mi < 4; ++mi)
        afr[mi] = *(const bf16x8*)(eb + (size_t)(wm * 64 + mi * 16 + l15) * 256 + choff);
      for (int ni = 0; ni < 4; ++ni)
        bfr[ni] = *(const bf16x8*)(vb2 + (size_t)(wn * 64 + ni * 16 + l15) * (TLEN * 2) + choff);
      for (int mi = 0; mi < 4; ++mi)
        for (int ni = 0; ni < 4; ++ni)
          accO[mi][ni] = __builtin_amdgcn_mfma_f32_16x16x32_bf16(afr[mi], bfr[ni], accO[mi][ni], 0, 0, 0);
    }
  }
  const bool excl = (it < 16);   // single contributing block -> plain store
  for (int mi = 0; mi < 4; ++mi)
    for (int ni = 0; ni < 4; ++ni) {
      int d = wn * 64 + ni * 16 + l15;
      for (int r = 0; r < 4; ++r) {
        int row = i0 + wm * 64 + mi * 16 + quad * 4 + r;
        float* dst = &out[((size_t)b * TLEN + row) * DDIM + d];
        if (excl) *dst = accO[mi][ni][r];
        else atomicAdd(dst, accO[mi][ni][r]);
      }
    }
}

// ---------------------------------------------------------------------------
extern "C" void kernel_launch(void* const* d_in, const int* in_sizes, int n_in,
                              void* d_out, int out_size, void* d_ws, size_t ws_size,
                              hipStream_t stream) {
  const float* x  = (const float*)d_in[0];
  const float* Wq = (const float*)d_in[1];
  const float* Wk = (const float*)d_in[2];
  const float* Wv = (const float*)d_in[3];
  float* out = (float*)d_out;

  u16* qb  = (u16*)d_ws;                       // [32768][128] bf16
  u16* kb  = qb  + (size_t)MROWS * DDIM;
  u16* vb  = kb  + (size_t)MROWS * DDIM;
  u16* vbT = vb  + (size_t)MROWS * DDIM;       // [8][128][4096]
  u16* Wt  = vbT + (size_t)MROWS * DDIM;       // [3][128][2048]
  float* denom = (float*)(Wt + (size_t)3 * DDIM * EDIM);  // [8][4096] fp32
  char* Epack = (char*)(denom + (size_t)BSZ * TLEN);      // 8*528*32KB = 135 MB

  hipLaunchKernelGGL(zero_f32, dim3(4096), dim3(256), 0, stream, out, denom);
  hipLaunchKernelGGL(prep_w, dim3(384), dim3(256), 0, stream, Wq, Wk, Wv, Wt);
  hipLaunchKernelGGL(qkv_gemm, dim3(256), dim3(512), 0, stream, x, Wt, qb);
  hipLaunchKernelGGL(score_k, dim3(NT, 4, BSZ), dim3(256), 0, stream, qb, kb, Epack, denom);
  hipLaunchKernelGGL(vscale_t, dim3(NT, BSZ), dim3(256), 0, stream, vb, denom, vbT);
  hipLaunchKernelGGL(pv_k, dim3(NT, 2, BSZ), dim3(256), 0, stream, Epack, vbT, out);
}